// Round 26
// baseline (267.968 us; speedup 1.0000x reference)
//
#include <hip/hip_runtime.h>
#include <hip/hip_bf16.h>
#include <math.h>

typedef __attribute__((ext_vector_type(8))) short bf16x8;
typedef __attribute__((ext_vector_type(4))) float f32x4;

static constexpr int kB = 4, kN = 1024, kC = 2048, kH = 16, kD = 128;
static constexpr int kM = kB * kN;   // 4096
static constexpr int k3C = 3 * kC;   // 6144

__device__ __forceinline__ short f2bf(float f) {
  unsigned u = __float_as_uint(f);
  u = (u + 0x7FFFu + ((u >> 16) & 1u)) >> 16;   // RNE
  return (short)u;
}

// ---------------- fused cast fp32 -> bf16 (3 segments, 1 launch) ----------------
__global__ __launch_bounds__(256) void cast3_f32_bf16(const float* __restrict__ a,
                                                      short* __restrict__ oa, int na4,
                                                      const float* __restrict__ b,
                                                      short* __restrict__ ob, int nb4,
                                                      const float* __restrict__ c,
                                                      short* __restrict__ oc, int nc4) {
  const int total = na4 + nb4 + nc4;
  const int stride = gridDim.x * blockDim.x;
  for (int i = blockIdx.x * blockDim.x + threadIdx.x; i < total; i += stride) {
    const float* in;
    short* out;
    int j = i;
    if (j < na4) {
      in = a; out = oa;
    } else if (j - na4 < nb4) {
      j -= na4; in = b; out = ob;
    } else {
      j -= na4 + nb4; in = c; out = oc;
    }
    float4 v = reinterpret_cast<const float4*>(in)[j];
    short4 o = make_short4(f2bf(v.x), f2bf(v.y), f2bf(v.z), f2bf(v.w));
    reinterpret_cast<short4*>(out)[j] = o;
  }
}

// --------- GEMM, 2-phase, BK templated (BK=64 r23/r24-verified win) ---------------
// 128x128 tile, 4 waves (2x2 of 64x64).
// Epilogue-transpose trick (r26): for q/k blocks and proj, accumulate with MFMA
// operands SWAPPED -> C^T in registers: per-thread row = lane&15, cols =
// (lane>>4)*4 + r (4 consecutive) -> packed short4/float4 row-major stores.
// v blocks (col0>=4096) keep normal order: per-thread 4 consecutive rows = 4
// consecutive vT pos -> packed short4 (r25-verified).
template <int EPI, int BK>
__global__ __launch_bounds__(256) void gemm_bt(const short* __restrict__ A,
                                               const short* __restrict__ Bt,
                                               const float* __restrict__ bias,
                                               void* __restrict__ out0,
                                               short* __restrict__ vT,
                                               int M, int N, int K) {
  constexpr int CH = BK / 8;            // 16B chunks per row
  constexpr int RPC = 64 / CH;          // rows per staging call
  constexpr int CALLS = 32 / RPC;       // calls per wave per matrix
  constexpr int KS = BK / 32;           // MFMA k-slices per tile
  __shared__ __align__(16) short As[2][128 * BK];
  __shared__ __align__(16) short Bs[2][128 * BK];
  const int lane = threadIdx.x & 63;
  const int wid = threadIdx.x >> 6;
  const int row0 = blockIdx.x * 128;
  const int col0 = blockIdx.y * 128;
  const int wrow = (wid >> 1) * 64;
  const int wcol = (wid & 1) * 64;
  f32x4 acc[4][4] = {};

  // swapped accumulation for row-major-packed epilogues (uniform per block)
  const bool swp = (EPI == 1) || (col0 < 4096);

  const int srow = lane / CH;
  const int skc = (lane & (CH - 1)) ^ (srow & (CH - 1));
  const short* Ag0 = A + (size_t)(row0 + wid * 32 + srow) * K + skc * 8;
  const short* Bg0 = Bt + (size_t)(col0 + wid * 32 + srow) * K + skc * 8;

#define GSTAGE(buf, k0)                                                                 \
  {                                                                                     \
    _Pragma("unroll") for (int c = 0; c < CALLS; ++c) {                                 \
      __builtin_amdgcn_global_load_lds(                                                 \
          (const __attribute__((address_space(1))) void*)(Ag0 + (size_t)c * RPC * K +   \
                                                          (k0)),                        \
          (__attribute__((address_space(3))) void*)&As[buf][(wid * 32 + c * RPC) * BK], \
          16, 0, 0);                                                                    \
    }                                                                                   \
    _Pragma("unroll") for (int c = 0; c < CALLS; ++c) {                                 \
      __builtin_amdgcn_global_load_lds(                                                 \
          (const __attribute__((address_space(1))) void*)(Bg0 + (size_t)c * RPC * K +   \
                                                          (k0)),                        \
          (__attribute__((address_space(3))) void*)&Bs[buf][(wid * 32 + c * RPC) * BK], \
          16, 0, 0);                                                                    \
    }                                                                                   \
  }

  GSTAGE(0, 0);
  __syncthreads();

  int cur = 0;
  for (int k0 = 0; k0 < K; k0 += BK) {
    if (k0 + BK < K) GSTAGE(cur ^ 1, k0 + BK);

    const char* abase = (const char*)&As[cur][0];
    const char* bbase = (const char*)&Bs[cur][0];
    bf16x8 af[4][KS], bfr[4][KS];
#pragma unroll
    for (int mt = 0; mt < 4; ++mt) {
      const int row = wrow + mt * 16 + (lane & 15);
#pragma unroll
      for (int ks = 0; ks < KS; ++ks) {
        const int pc = (ks * 4 + (lane >> 4)) ^ (row & (CH - 1));
        af[mt][ks] = *(const bf16x8*)(abase + row * (BK * 2) + pc * 16);
      }
    }
#pragma unroll
    for (int nt = 0; nt < 4; ++nt) {
      const int col = wcol + nt * 16 + (lane & 15);
#pragma unroll
      for (int ks = 0; ks < KS; ++ks) {
        const int pc = (ks * 4 + (lane >> 4)) ^ (col & (CH - 1));
        bfr[nt][ks] = *(const bf16x8*)(bbase + col * (BK * 2) + pc * 16);
      }
    }
    if (swp) {
#pragma unroll
      for (int mt = 0; mt < 4; ++mt)
#pragma unroll
        for (int nt = 0; nt < 4; ++nt)
#pragma unroll
          for (int ks = 0; ks < KS; ++ks)
            acc[mt][nt] = __builtin_amdgcn_mfma_f32_16x16x32_bf16(bfr[nt][ks], af[mt][ks],
                                                                  acc[mt][nt], 0, 0, 0);
    } else {
#pragma unroll
      for (int mt = 0; mt < 4; ++mt)
#pragma unroll
        for (int nt = 0; nt < 4; ++nt)
#pragma unroll
          for (int ks = 0; ks < KS; ++ks)
            acc[mt][nt] = __builtin_amdgcn_mfma_f32_16x16x32_bf16(af[mt][ks], bfr[nt][ks],
                                                                  acc[mt][nt], 0, 0, 0);
    }

    __syncthreads();
    cur ^= 1;
  }
#undef GSTAGE

  if (EPI == 0) {
    if (col0 < 4096) {
      // swapped C^T: row = lane&15, 4 consecutive cols -> packed short4 stores
      short* qk = (short*)out0;
#pragma unroll
      for (int mt = 0; mt < 4; ++mt) {
#pragma unroll
        for (int nt = 0; nt < 4; ++nt) {
          int row = row0 + wrow + mt * 16 + (lane & 15);
          int colb = col0 + wcol + nt * 16 + (lane >> 4) * 4;
          float4 bv = *(const float4*)&bias[colb];
          short4 pk = make_short4(f2bf(acc[mt][nt][0] + bv.x), f2bf(acc[mt][nt][1] + bv.y),
                                  f2bf(acc[mt][nt][2] + bv.z), f2bf(acc[mt][nt][3] + bv.w));
          *(short4*)&qk[(size_t)row * 4096 + colb] = pk;
        }
      }
    } else {
      // v block, normal order: 4 consecutive rows = 4 consecutive pos (r25)
#pragma unroll
      for (int mt = 0; mt < 4; ++mt) {
#pragma unroll
        for (int nt = 0; nt < 4; ++nt) {
          int col = col0 + wcol + nt * 16 + (lane & 15);
          float bv = bias[col];
          int rbase = row0 + wrow + mt * 16 + (lane >> 4) * 4;
          int b = rbase >> 10, pos0 = rbase & 1023;
          int hd = col - 4096;
          short4 pk = make_short4(f2bf(acc[mt][nt][0] + bv), f2bf(acc[mt][nt][1] + bv),
                                  f2bf(acc[mt][nt][2] + bv), f2bf(acc[mt][nt][3] + bv));
          *(short4*)&vT[((size_t)b * 2048 + hd) * 1024 + pos0] = pk;
        }
      }
    }
  } else {
    // proj, swapped C^T: packed float4 stores
    float* out = (float*)out0;
#pragma unroll
    for (int mt = 0; mt < 4; ++mt) {
#pragma unroll
      for (int nt = 0; nt < 4; ++nt) {
        int row = row0 + wrow + mt * 16 + (lane & 15);
        int colb = col0 + wcol + nt * 16 + (lane >> 4) * 4;
        float4 bv = *(const float4*)&bias[colb];
        float4 o;
        o.x = acc[mt][nt][0] + bv.x;
        o.y = acc[mt][nt][1] + bv.y;
        o.z = acc[mt][nt][2] + bv.z;
        o.w = acc[mt][nt][3] + bv.w;
        *(float4*)&out[(size_t)row * N + colb] = o;
      }
    }
  }
}

// ---------------- flash attention v4: QBLK=128, 2 q-strips per wave (r20 best) ----
__global__ __launch_bounds__(256) void attn_kernel(const short* __restrict__ qk,
                                                   const short* __restrict__ vT,
                                                   short* __restrict__ att) {
  __shared__ __align__(16) short Ks[2][64][128];
  __shared__ __align__(16) short Vs[2][128][64];
  __shared__ __align__(16) short P[4][16][72];
  const int lane = threadIdx.x & 63;
  const int wid = threadIdx.x >> 6;
  const int bh = blockIdx.y;
  const int b = bh >> 4, h = bh & 15;
  const int q0 = blockIdx.x * 128 + wid * 16;

  const short* qbase = qk + (size_t)(b * 1024) * 4096 + h * 128;
  const short* kglob = qbase + 2048;
  const short* vglob = vT + (size_t)bh * 128 * 1024;

  bf16x8 qf[2][4];
#pragma unroll
  for (int s = 0; s < 2; ++s) {
    const int qrow = q0 + s * 64 + (lane & 15);
#pragma unroll
    for (int dc = 0; dc < 4; ++dc)
      qf[s][dc] = *(const bf16x8*)&qbase[(size_t)qrow * 4096 + dc * 32 + (lane >> 4) * 8];
  }

  const int krow_l = wid * 16 + (lane >> 4);
  const int kcol_l = (lane & 15) << 4;
  const int vrow_l = wid * 32 + (lane >> 3);
  const int vcol_l = (lane & 7) << 4;

#define STAGE_KV(buf, kv0)                                                              \
  {                                                                                     \
    _Pragma("unroll") for (int i = 0; i < 4; ++i) {                                     \
      int r = krow_l + i * 4;                                                           \
      const char* src = (const char*)(kglob + (size_t)((kv0) + r) * 4096) +             \
                        (kcol_l ^ ((r & 7) << 4));                                      \
      __builtin_amdgcn_global_load_lds(                                                 \
          (const __attribute__((address_space(1))) void*)src,                           \
          (__attribute__((address_space(3))) void*)&Ks[buf][wid * 16 + i * 4][0], 16,   \
          0, 0);                                                                        \
    }                                                                                   \
    _Pragma("unroll") for (int i = 0; i < 4; ++i) {                                     \
      int d = vrow_l + i * 8;                                                           \
      const char* src = (const char*)(vglob + (size_t)d * 1024 + (kv0)) +               \
                        (vcol_l ^ ((d & 7) << 4));                                      \
      __builtin_amdgcn_global_load_lds(                                                 \
          (const __attribute__((address_space(1))) void*)src,                           \
          (__attribute__((address_space(3))) void*)&Vs[buf][wid * 32 + i * 8][0], 16,   \
          0, 0);                                                                        \
    }                                                                                   \
  }

  float l_r[2][4] = {};
  f32x4 accO[2][8] = {};

  const float scale = 0.08838834764831845f;  // 1/sqrt(128)

  STAGE_KV(0, 0);
  asm volatile("s_waitcnt vmcnt(0)" ::: "memory");
  __builtin_amdgcn_s_barrier();
  __builtin_amdgcn_sched_barrier(0);

  int cur = 0;
  for (int t = 0; t < 16; ++t) {
    if (t < 15) STAGE_KV(cur ^ 1, (t + 1) * 64);

#pragma unroll
    for (int s = 0; s < 2; ++s) {
      f32x4 s4[4] = {};
#pragma unroll
      for (int kt = 0; kt < 4; ++kt) {
        const int row = kt * 16 + (lane & 15);
        const char* kr = (const char*)&Ks[cur][row][0];
        const int swz = (row & 7) << 4;
#pragma unroll
        for (int dc = 0; dc < 4; ++dc) {
          bf16x8 kf = *(const bf16x8*)(kr + ((dc * 64 + (lane >> 4) * 16) ^ swz));
          s4[kt] = __builtin_amdgcn_mfma_f32_16x16x32_bf16(qf[s][dc], kf, s4[kt], 0, 0, 0);
        }
      }

#pragma unroll
      for (int r = 0; r < 4; ++r) {
        float p0 = __expf(s4[0][r] * scale);
        float p1 = __expf(s4[1][r] * scale);
        float p2 = __expf(s4[2][r] * scale);
        float p3 = __expf(s4[3][r] * scale);
        l_r[s][r] += (p0 + p1) + (p2 + p3);
        int prow = (lane >> 4) * 4 + r;
        P[wid][prow][(lane & 15)] = f2bf(p0);
        P[wid][prow][16 + (lane & 15)] = f2bf(p1);
        P[wid][prow][32 + (lane & 15)] = f2bf(p2);
        P[wid][prow][48 + (lane & 15)] = f2bf(p3);
      }

      bf16x8 pf0 = *(const bf16x8*)&P[wid][lane & 15][(lane >> 4) * 8];
      bf16x8 pf1 = *(const bf16x8*)&P[wid][lane & 15][32 + (lane >> 4) * 8];

#pragma unroll
      for (int d0 = 0; d0 < 8; ++d0) {
        const int d = d0 * 16 + (lane & 15);
        const char* vr = (const char*)&Vs[cur][d][0];
        const int swz = (d & 7) << 4;
        bf16x8 vf0 = *(const bf16x8*)(vr + (((lane >> 4) * 16) ^ swz));
        bf16x8 vf1 = *(const bf16x8*)(vr + ((64 + (lane >> 4) * 16) ^ swz));
        accO[s][d0] = __builtin_amdgcn_mfma_f32_16x16x32_bf16(pf0, vf0, accO[s][d0], 0, 0, 0);
        accO[s][d0] = __builtin_amdgcn_mfma_f32_16x16x32_bf16(pf1, vf1, accO[s][d0], 0, 0, 0);
      }
    }

    asm volatile("s_waitcnt vmcnt(0)" ::: "memory");
    __builtin_amdgcn_s_barrier();
    __builtin_amdgcn_sched_barrier(0);
    cur ^= 1;
  }
#undef STAGE_KV

#pragma unroll
  for (int s = 0; s < 2; ++s) {
    float invl[4];
#pragma unroll
    for (int r = 0; r < 4; ++r) {
      float sum = l_r[s][r];
#pragma unroll
      for (int off = 1; off < 16; off <<= 1) sum += __shfl_xor(sum, off);
      invl[r] = 1.0f / sum;
    }
#pragma unroll
    for (int d0 = 0; d0 < 8; ++d0) {
#pragma unroll
      for (int r = 0; r < 4; ++r) {
        int arow = q0 + s * 64 + (lane >> 4) * 4 + r;
        att[(size_t)(b * 1024 + arow) * 2048 + h * 128 + d0 * 16 + (lane & 15)] =
            f2bf(accO[s][d0][r] * invl[r]);
      }
    }
  }
}

// ---------------- launch ----------------
extern "C" void kernel_launch(void* const* d_in, const int* in_sizes, int n_in,
                              void* d_out, int out_size, void* d_ws, size_t ws_size,
                              hipStream_t stream) {
  const float* x = (const float*)d_in[0];
  const float* Wqkv = (const float*)d_in[1];
  const float* bqkv = (const float*)d_in[2];
  const float* Wproj = (const float*)d_in[3];
  const float* bproj = (const float*)d_in[4];
  // d_in[5] = noise: provably unused (imag part never reaches the real output)
  float* out = (float*)d_out;

  char* ws = (char*)d_ws;
  short* xb = (short*)(ws + 0);
  short* Wqkvb = (short*)(ws + 16777216);
  short* Wprojb = (short*)(ws + 41943040);
  short* qkbuf = (short*)(ws + 50331648);
  short* vT = (short*)(ws + 83886080);
  short* attb = (short*)(ws + 100663296);

  hipLaunchKernelGGL(cast3_f32_bf16, dim3(3072), dim3(256), 0, stream,
                     x, xb, kM * kC / 4,
                     Wqkv, Wqkvb, k3C * kC / 4,
                     Wproj, Wprojb, kC * kC / 4);

  // QKV: BK=64 + swapped-C^T packed q/k stores + packed vT stores
  hipLaunchKernelGGL((gemm_bt<0, 64>), dim3(kM / 128, k3C / 128), dim3(256), 0, stream,
                     xb, Wqkvb, bqkv, (void*)qkbuf, vT, kM, k3C, kC);

  hipLaunchKernelGGL(attn_kernel, dim3(kN / 128, kB * kH), dim3(256), 0, stream,
                     qkbuf, vT, attb);

  // proj: BK=64 + swapped-C^T packed float4 stores
  hipLaunchKernelGGL((gemm_bt<1, 64>), dim3(kM / 128, kC / 128), dim3(256), 0, stream,
                     attb, Wprojb, bproj, (void*)out, (short*)nullptr, kM, kC, kC);
}

// Round 27
// 248.508 us; speedup vs baseline: 1.0783x; 1.0783x over previous
//
#include <hip/hip_runtime.h>
#include <hip/hip_bf16.h>
#include <math.h>

typedef __attribute__((ext_vector_type(8))) short bf16x8;
typedef __attribute__((ext_vector_type(4))) float f32x4;

static constexpr int kB = 4, kN = 1024, kC = 2048, kH = 16, kD = 128;
static constexpr int kM = kB * kN;   // 4096
static constexpr int k3C = 3 * kC;   // 6144

__device__ __forceinline__ short f2bf(float f) {
  unsigned u = __float_as_uint(f);
  u = (u + 0x7FFFu + ((u >> 16) & 1u)) >> 16;   // RNE
  return (short)u;
}

// ---------------- fused cast fp32 -> bf16 (3 segments, 1 launch) ----------------
__global__ __launch_bounds__(256) void cast3_f32_bf16(const float* __restrict__ a,
                                                      short* __restrict__ oa, int na4,
                                                      const float* __restrict__ b,
                                                      short* __restrict__ ob, int nb4,
                                                      const float* __restrict__ c,
                                                      short* __restrict__ oc, int nc4) {
  const int total = na4 + nb4 + nc4;
  const int stride = gridDim.x * blockDim.x;
  for (int i = blockIdx.x * blockDim.x + threadIdx.x; i < total; i += stride) {
    const float* in;
    short* out;
    int j = i;
    if (j < na4) {
      in = a; out = oa;
    } else if (j - na4 < nb4) {
      j -= na4; in = b; out = ob;
    } else {
      j -= na4 + nb4; in = c; out = oc;
    }
    float4 v = reinterpret_cast<const float4*>(in)[j];
    short4 o = make_short4(f2bf(v.x), f2bf(v.y), f2bf(v.z), f2bf(v.w));
    reinterpret_cast<short4*>(out)[j] = o;
  }
}

// --------- GEMM, 2-phase, BK=64 (r23/r24), COMPILE-TIME swap (r26 lesson) ---------
// 128x128 tile, 4 waves (2x2 of 64x64).
// SWAP=true: accumulate mfma(B,A) -> C^T in regs: per-thread row = lane&15,
//   4 consecutive cols = (lane>>4)*4+r -> packed row-major stores.
// EPI 0: qk panels, SWAP, packed short4.  EPI 2: v panels, no swap, packed vT
//   short4 (4 consecutive pos).  EPI 1: proj, SWAP, packed float4.
// r26 lesson: swap MUST be compile-time — a runtime-uniform branch around the
// MFMA loop duplicated the body (VGPR 96->112, VALUBusy 48%, +25us).
template <int EPI, int BK, bool SWAP>
__global__ __launch_bounds__(256) void gemm_bt(const short* __restrict__ A,
                                               const short* __restrict__ Bt,
                                               const float* __restrict__ bias,
                                               void* __restrict__ out0,
                                               short* __restrict__ vT,
                                               int M, int N, int K) {
  constexpr int CH = BK / 8;
  constexpr int RPC = 64 / CH;
  constexpr int CALLS = 32 / RPC;
  constexpr int KS = BK / 32;
  __shared__ __align__(16) short As[2][128 * BK];
  __shared__ __align__(16) short Bs[2][128 * BK];
  const int lane = threadIdx.x & 63;
  const int wid = threadIdx.x >> 6;
  const int row0 = blockIdx.x * 128;
  const int col0 = blockIdx.y * 128;
  const int wrow = (wid >> 1) * 64;
  const int wcol = (wid & 1) * 64;
  f32x4 acc[4][4] = {};

  const int srow = lane / CH;
  const int skc = (lane & (CH - 1)) ^ (srow & (CH - 1));
  const short* Ag0 = A + (size_t)(row0 + wid * 32 + srow) * K + skc * 8;
  const short* Bg0 = Bt + (size_t)(col0 + wid * 32 + srow) * K + skc * 8;

#define GSTAGE(buf, k0)                                                                 \
  {                                                                                     \
    _Pragma("unroll") for (int c = 0; c < CALLS; ++c) {                                 \
      __builtin_amdgcn_global_load_lds(                                                 \
          (const __attribute__((address_space(1))) void*)(Ag0 + (size_t)c * RPC * K +   \
                                                          (k0)),                        \
          (__attribute__((address_space(3))) void*)&As[buf][(wid * 32 + c * RPC) * BK], \
          16, 0, 0);                                                                    \
    }                                                                                   \
    _Pragma("unroll") for (int c = 0; c < CALLS; ++c) {                                 \
      __builtin_amdgcn_global_load_lds(                                                 \
          (const __attribute__((address_space(1))) void*)(Bg0 + (size_t)c * RPC * K +   \
                                                          (k0)),                        \
          (__attribute__((address_space(3))) void*)&Bs[buf][(wid * 32 + c * RPC) * BK], \
          16, 0, 0);                                                                    \
    }                                                                                   \
  }

  GSTAGE(0, 0);
  __syncthreads();

  int cur = 0;
  for (int k0 = 0; k0 < K; k0 += BK) {
    if (k0 + BK < K) GSTAGE(cur ^ 1, k0 + BK);

    const char* abase = (const char*)&As[cur][0];
    const char* bbase = (const char*)&Bs[cur][0];
    bf16x8 af[4][KS], bfr[4][KS];
#pragma unroll
    for (int mt = 0; mt < 4; ++mt) {
      const int row = wrow + mt * 16 + (lane & 15);
#pragma unroll
      for (int ks = 0; ks < KS; ++ks) {
        const int pc = (ks * 4 + (lane >> 4)) ^ (row & (CH - 1));
        af[mt][ks] = *(const bf16x8*)(abase + row * (BK * 2) + pc * 16);
      }
    }
#pragma unroll
    for (int nt = 0; nt < 4; ++nt) {
      const int col = wcol + nt * 16 + (lane & 15);
#pragma unroll
      for (int ks = 0; ks < KS; ++ks) {
        const int pc = (ks * 4 + (lane >> 4)) ^ (col & (CH - 1));
        bfr[nt][ks] = *(const bf16x8*)(bbase + col * (BK * 2) + pc * 16);
      }
    }
#pragma unroll
    for (int mt = 0; mt < 4; ++mt)
#pragma unroll
      for (int nt = 0; nt < 4; ++nt)
#pragma unroll
        for (int ks = 0; ks < KS; ++ks) {
          if (SWAP)
            acc[mt][nt] = __builtin_amdgcn_mfma_f32_16x16x32_bf16(bfr[nt][ks], af[mt][ks],
                                                                  acc[mt][nt], 0, 0, 0);
          else
            acc[mt][nt] = __builtin_amdgcn_mfma_f32_16x16x32_bf16(af[mt][ks], bfr[nt][ks],
                                                                  acc[mt][nt], 0, 0, 0);
        }

    __syncthreads();
    cur ^= 1;
  }
#undef GSTAGE

  if (EPI == 0) {
    // qk panels, SWAP: row = lane&15, 4 consecutive cols -> packed short4
    short* qk = (short*)out0;
#pragma unroll
    for (int mt = 0; mt < 4; ++mt) {
#pragma unroll
      for (int nt = 0; nt < 4; ++nt) {
        int row = row0 + wrow + mt * 16 + (lane & 15);
        int colb = col0 + wcol + nt * 16 + (lane >> 4) * 4;
        float4 bv = *(const float4*)&bias[colb];
        short4 pk = make_short4(f2bf(acc[mt][nt][0] + bv.x), f2bf(acc[mt][nt][1] + bv.y),
                                f2bf(acc[mt][nt][2] + bv.z), f2bf(acc[mt][nt][3] + bv.w));
        *(short4*)&qk[(size_t)row * 4096 + colb] = pk;
      }
    }
  } else if (EPI == 2) {
    // v panels, no swap: 4 consecutive rows = 4 consecutive pos (r25)
#pragma unroll
    for (int mt = 0; mt < 4; ++mt) {
#pragma unroll
      for (int nt = 0; nt < 4; ++nt) {
        int col = col0 + wcol + nt * 16 + (lane & 15);   // hd = col (0..2047)
        float bv = bias[col];
        int rbase = row0 + wrow + mt * 16 + (lane >> 4) * 4;
        int b = rbase >> 10, pos0 = rbase & 1023;
        short4 pk = make_short4(f2bf(acc[mt][nt][0] + bv), f2bf(acc[mt][nt][1] + bv),
                                f2bf(acc[mt][nt][2] + bv), f2bf(acc[mt][nt][3] + bv));
        *(short4*)&vT[((size_t)b * 2048 + col) * 1024 + pos0] = pk;
      }
    }
  } else {
    // proj, SWAP: packed float4
    float* out = (float*)out0;
#pragma unroll
    for (int mt = 0; mt < 4; ++mt) {
#pragma unroll
      for (int nt = 0; nt < 4; ++nt) {
        int row = row0 + wrow + mt * 16 + (lane & 15);
        int colb = col0 + wcol + nt * 16 + (lane >> 4) * 4;
        float4 bv = *(const float4*)&bias[colb];
        float4 o;
        o.x = acc[mt][nt][0] + bv.x;
        o.y = acc[mt][nt][1] + bv.y;
        o.z = acc[mt][nt][2] + bv.z;
        o.w = acc[mt][nt][3] + bv.w;
        *(float4*)&out[(size_t)row * N + colb] = o;
      }
    }
  }
}

// ---------------- flash attention v4: QBLK=128, 2 q-strips per wave (r20 best) ----
__global__ __launch_bounds__(256) void attn_kernel(const short* __restrict__ qk,
                                                   const short* __restrict__ vT,
                                                   short* __restrict__ att) {
  __shared__ __align__(16) short Ks[2][64][128];
  __shared__ __align__(16) short Vs[2][128][64];
  __shared__ __align__(16) short P[4][16][72];
  const int lane = threadIdx.x & 63;
  const int wid = threadIdx.x >> 6;
  const int bh = blockIdx.y;
  const int b = bh >> 4, h = bh & 15;
  const int q0 = blockIdx.x * 128 + wid * 16;

  const short* qbase = qk + (size_t)(b * 1024) * 4096 + h * 128;
  const short* kglob = qbase + 2048;
  const short* vglob = vT + (size_t)bh * 128 * 1024;

  bf16x8 qf[2][4];
#pragma unroll
  for (int s = 0; s < 2; ++s) {
    const int qrow = q0 + s * 64 + (lane & 15);
#pragma unroll
    for (int dc = 0; dc < 4; ++dc)
      qf[s][dc] = *(const bf16x8*)&qbase[(size_t)qrow * 4096 + dc * 32 + (lane >> 4) * 8];
  }

  const int krow_l = wid * 16 + (lane >> 4);
  const int kcol_l = (lane & 15) << 4;
  const int vrow_l = wid * 32 + (lane >> 3);
  const int vcol_l = (lane & 7) << 4;

#define STAGE_KV(buf, kv0)                                                              \
  {                                                                                     \
    _Pragma("unroll") for (int i = 0; i < 4; ++i) {                                     \
      int r = krow_l + i * 4;                                                           \
      const char* src = (const char*)(kglob + (size_t)((kv0) + r) * 4096) +             \
                        (kcol_l ^ ((r & 7) << 4));                                      \
      __builtin_amdgcn_global_load_lds(                                                 \
          (const __attribute__((address_space(1))) void*)src,                           \
          (__attribute__((address_space(3))) void*)&Ks[buf][wid * 16 + i * 4][0], 16,   \
          0, 0);                                                                        \
    }                                                                                   \
    _Pragma("unroll") for (int i = 0; i < 4; ++i) {                                     \
      int d = vrow_l + i * 8;                                                           \
      const char* src = (const char*)(vglob + (size_t)d * 1024 + (kv0)) +               \
                        (vcol_l ^ ((d & 7) << 4));                                      \
      __builtin_amdgcn_global_load_lds(                                                 \
          (const __attribute__((address_space(1))) void*)src,                           \
          (__attribute__((address_space(3))) void*)&Vs[buf][wid * 32 + i * 8][0], 16,   \
          0, 0);                                                                        \
    }                                                                                   \
  }

  float l_r[2][4] = {};
  f32x4 accO[2][8] = {};

  const float scale = 0.08838834764831845f;  // 1/sqrt(128)

  STAGE_KV(0, 0);
  asm volatile("s_waitcnt vmcnt(0)" ::: "memory");
  __builtin_amdgcn_s_barrier();
  __builtin_amdgcn_sched_barrier(0);

  int cur = 0;
  for (int t = 0; t < 16; ++t) {
    if (t < 15) STAGE_KV(cur ^ 1, (t + 1) * 64);

#pragma unroll
    for (int s = 0; s < 2; ++s) {
      f32x4 s4[4] = {};
#pragma unroll
      for (int kt = 0; kt < 4; ++kt) {
        const int row = kt * 16 + (lane & 15);
        const char* kr = (const char*)&Ks[cur][row][0];
        const int swz = (row & 7) << 4;
#pragma unroll
        for (int dc = 0; dc < 4; ++dc) {
          bf16x8 kf = *(const bf16x8*)(kr + ((dc * 64 + (lane >> 4) * 16) ^ swz));
          s4[kt] = __builtin_amdgcn_mfma_f32_16x16x32_bf16(qf[s][dc], kf, s4[kt], 0, 0, 0);
        }
      }

#pragma unroll
      for (int r = 0; r < 4; ++r) {
        float p0 = __expf(s4[0][r] * scale);
        float p1 = __expf(s4[1][r] * scale);
        float p2 = __expf(s4[2][r] * scale);
        float p3 = __expf(s4[3][r] * scale);
        l_r[s][r] += (p0 + p1) + (p2 + p3);
        int prow = (lane >> 4) * 4 + r;
        P[wid][prow][(lane & 15)] = f2bf(p0);
        P[wid][prow][16 + (lane & 15)] = f2bf(p1);
        P[wid][prow][32 + (lane & 15)] = f2bf(p2);
        P[wid][prow][48 + (lane & 15)] = f2bf(p3);
      }

      bf16x8 pf0 = *(const bf16x8*)&P[wid][lane & 15][(lane >> 4) * 8];
      bf16x8 pf1 = *(const bf16x8*)&P[wid][lane & 15][32 + (lane >> 4) * 8];

#pragma unroll
      for (int d0 = 0; d0 < 8; ++d0) {
        const int d = d0 * 16 + (lane & 15);
        const char* vr = (const char*)&Vs[cur][d][0];
        const int swz = (d & 7) << 4;
        bf16x8 vf0 = *(const bf16x8*)(vr + (((lane >> 4) * 16) ^ swz));
        bf16x8 vf1 = *(const bf16x8*)(vr + ((64 + (lane >> 4) * 16) ^ swz));
        accO[s][d0] = __builtin_amdgcn_mfma_f32_16x16x32_bf16(pf0, vf0, accO[s][d0], 0, 0, 0);
        accO[s][d0] = __builtin_amdgcn_mfma_f32_16x16x32_bf16(pf1, vf1, accO[s][d0], 0, 0, 0);
      }
    }

    asm volatile("s_waitcnt vmcnt(0)" ::: "memory");
    __builtin_amdgcn_s_barrier();
    __builtin_amdgcn_sched_barrier(0);
    cur ^= 1;
  }
#undef STAGE_KV

#pragma unroll
  for (int s = 0; s < 2; ++s) {
    float invl[4];
#pragma unroll
    for (int r = 0; r < 4; ++r) {
      float sum = l_r[s][r];
#pragma unroll
      for (int off = 1; off < 16; off <<= 1) sum += __shfl_xor(sum, off);
      invl[r] = 1.0f / sum;
    }
#pragma unroll
    for (int d0 = 0; d0 < 8; ++d0) {
#pragma unroll
      for (int r = 0; r < 4; ++r) {
        int arow = q0 + s * 64 + (lane >> 4) * 4 + r;
        att[(size_t)(b * 1024 + arow) * 2048 + h * 128 + d0 * 16 + (lane & 15)] =
            f2bf(accO[s][d0][r] * invl[r]);
      }
    }
  }
}

// ---------------- launch ----------------
extern "C" void kernel_launch(void* const* d_in, const int* in_sizes, int n_in,
                              void* d_out, int out_size, void* d_ws, size_t ws_size,
                              hipStream_t stream) {
  const float* x = (const float*)d_in[0];
  const float* Wqkv = (const float*)d_in[1];
  const float* bqkv = (const float*)d_in[2];
  const float* Wproj = (const float*)d_in[3];
  const float* bproj = (const float*)d_in[4];
  // d_in[5] = noise: provably unused (imag part never reaches the real output)
  float* out = (float*)d_out;

  char* ws = (char*)d_ws;
  short* xb = (short*)(ws + 0);
  short* Wqkvb = (short*)(ws + 16777216);
  short* Wprojb = (short*)(ws + 41943040);
  short* qkbuf = (short*)(ws + 50331648);
  short* vT = (short*)(ws + 83886080);
  short* attb = (short*)(ws + 100663296);

  hipLaunchKernelGGL(cast3_f32_bf16, dim3(3072), dim3(256), 0, stream,
                     x, xb, kM * kC / 4,
                     Wqkv, Wqkvb, k3C * kC / 4,
                     Wproj, Wprojb, kC * kC / 4);

  // QKV split by epilogue (compile-time swap, no runtime branch):
  // q/k panels: cols 0..4095, swapped C^T, packed short4. grid 32 x 32.
  hipLaunchKernelGGL((gemm_bt<0, 64, true>), dim3(kM / 128, 4096 / 128), dim3(256), 0,
                     stream, xb, Wqkvb, bqkv, (void*)qkbuf, (short*)nullptr,
                     kM, 4096, kC);
  // v panels: cols 4096..6143 (Bt/bias offset), normal order, packed vT. grid 32 x 16.
  hipLaunchKernelGGL((gemm_bt<2, 64, false>), dim3(kM / 128, 2048 / 128), dim3(256), 0,
                     stream, xb, Wqkvb + (size_t)4096 * kC, bqkv + 4096, (void*)nullptr,
                     vT, kM, 2048, kC);

  hipLaunchKernelGGL(attn_kernel, dim3(kN / 128, kB * kH), dim3(256), 0, stream,
                     qkbuf, vT, attb);

  // proj: swapped C^T, packed float4. grid 32 x 16.
  hipLaunchKernelGGL((gemm_bt<1, 64, true>), dim3(kM / 128, kC / 128), dim3(256), 0,
                     stream, attb, Wprojb, bproj, (void*)out, (short*)nullptr,
                     kM, kC, kC);
}

// Round 28
// 242.354 us; speedup vs baseline: 1.1057x; 1.0254x over previous
//
#include <hip/hip_runtime.h>
#include <hip/hip_bf16.h>
#include <math.h>

typedef __attribute__((ext_vector_type(8))) short bf16x8;
typedef __attribute__((ext_vector_type(4))) float f32x4;

static constexpr int kB = 4, kN = 1024, kC = 2048, kH = 16, kD = 128;
static constexpr int kM = kB * kN;   // 4096
static constexpr int k3C = 3 * kC;   // 6144

__device__ __forceinline__ short f2bf(float f) {
  unsigned u = __float_as_uint(f);
  u = (u + 0x7FFFu + ((u >> 16) & 1u)) >> 16;   // RNE
  return (short)u;
}

// ---------------- fused cast fp32 -> bf16 (3 segments, 1 launch) ----------------
__global__ __launch_bounds__(256) void cast3_f32_bf16(const float* __restrict__ a,
                                                      short* __restrict__ oa, int na4,
                                                      const float* __restrict__ b,
                                                      short* __restrict__ ob, int nb4,
                                                      const float* __restrict__ c,
                                                      short* __restrict__ oc, int nc4) {
  const int total = na4 + nb4 + nc4;
  const int stride = gridDim.x * blockDim.x;
  for (int i = blockIdx.x * blockDim.x + threadIdx.x; i < total; i += stride) {
    const float* in;
    short* out;
    int j = i;
    if (j < na4) {
      in = a; out = oa;
    } else if (j - na4 < nb4) {
      j -= na4; in = b; out = ob;
    } else {
      j -= na4 + nb4; in = c; out = oc;
    }
    float4 v = reinterpret_cast<const float4*>(in)[j];
    short4 o = make_short4(f2bf(v.x), f2bf(v.y), f2bf(v.z), f2bf(v.w));
    reinterpret_cast<short4*>(out)[j] = o;
  }
}

// --------- GEMM, 2-phase, BK templated (BK=64 r23/r24-verified win) ---------------
// 128x128 tile, 4 waves (2x2 of 64x64). LDS row = BK shorts.
//   BK=64: stage lane -> row l>>3, chunk l&7, src chunk (l&7)^(l>>3)
//   read phys chunk = (ks*4+(lane>>4)) ^ (row & (CH-1)) — conflict-free.
// r26/r27 lesson: swapped-operand epilogue (C^T packing) is net-negative in both
// runtime-branch and compile-time-split forms; only the vT scatter packing pays.
template <int EPI, int BK>
__global__ __launch_bounds__(256) void gemm_bt(const short* __restrict__ A,
                                               const short* __restrict__ Bt,
                                               const float* __restrict__ bias,
                                               void* __restrict__ out0,
                                               short* __restrict__ vT,
                                               int M, int N, int K) {
  constexpr int CH = BK / 8;            // 16B chunks per row
  constexpr int RPC = 64 / CH;          // rows per staging call
  constexpr int CALLS = 32 / RPC;       // calls per wave per matrix
  constexpr int KS = BK / 32;           // MFMA k-slices per tile
  __shared__ __align__(16) short As[2][128 * BK];
  __shared__ __align__(16) short Bs[2][128 * BK];
  const int lane = threadIdx.x & 63;
  const int wid = threadIdx.x >> 6;
  const int row0 = blockIdx.x * 128;
  const int col0 = blockIdx.y * 128;
  const int wrow = (wid >> 1) * 64;
  const int wcol = (wid & 1) * 64;
  f32x4 acc[4][4] = {};

  const int srow = lane / CH;
  const int skc = (lane & (CH - 1)) ^ (srow & (CH - 1));
  const short* Ag0 = A + (size_t)(row0 + wid * 32 + srow) * K + skc * 8;
  const short* Bg0 = Bt + (size_t)(col0 + wid * 32 + srow) * K + skc * 8;

#define GSTAGE(buf, k0)                                                                 \
  {                                                                                     \
    _Pragma("unroll") for (int c = 0; c < CALLS; ++c) {                                 \
      __builtin_amdgcn_global_load_lds(                                                 \
          (const __attribute__((address_space(1))) void*)(Ag0 + (size_t)c * RPC * K +   \
                                                          (k0)),                        \
          (__attribute__((address_space(3))) void*)&As[buf][(wid * 32 + c * RPC) * BK], \
          16, 0, 0);                                                                    \
    }                                                                                   \
    _Pragma("unroll") for (int c = 0; c < CALLS; ++c) {                                 \
      __builtin_amdgcn_global_load_lds(                                                 \
          (const __attribute__((address_space(1))) void*)(Bg0 + (size_t)c * RPC * K +   \
                                                          (k0)),                        \
          (__attribute__((address_space(3))) void*)&Bs[buf][(wid * 32 + c * RPC) * BK], \
          16, 0, 0);                                                                    \
    }                                                                                   \
  }

  GSTAGE(0, 0);
  __syncthreads();

  int cur = 0;
  for (int k0 = 0; k0 < K; k0 += BK) {
    if (k0 + BK < K) GSTAGE(cur ^ 1, k0 + BK);

    const char* abase = (const char*)&As[cur][0];
    const char* bbase = (const char*)&Bs[cur][0];
    bf16x8 af[4][KS], bfr[4][KS];
#pragma unroll
    for (int mt = 0; mt < 4; ++mt) {
      const int row = wrow + mt * 16 + (lane & 15);
#pragma unroll
      for (int ks = 0; ks < KS; ++ks) {
        const int pc = (ks * 4 + (lane >> 4)) ^ (row & (CH - 1));
        af[mt][ks] = *(const bf16x8*)(abase + row * (BK * 2) + pc * 16);
      }
    }
#pragma unroll
    for (int nt = 0; nt < 4; ++nt) {
      const int col = wcol + nt * 16 + (lane & 15);
#pragma unroll
      for (int ks = 0; ks < KS; ++ks) {
        const int pc = (ks * 4 + (lane >> 4)) ^ (col & (CH - 1));
        bfr[nt][ks] = *(const bf16x8*)(bbase + col * (BK * 2) + pc * 16);
      }
    }
#pragma unroll
    for (int mt = 0; mt < 4; ++mt)
#pragma unroll
      for (int nt = 0; nt < 4; ++nt)
#pragma unroll
        for (int ks = 0; ks < KS; ++ks)
          acc[mt][nt] = __builtin_amdgcn_mfma_f32_16x16x32_bf16(af[mt][ks], bfr[nt][ks],
                                                                acc[mt][nt], 0, 0, 0);

    __syncthreads();
    cur ^= 1;
  }
#undef GSTAGE

  if (EPI == 0) {
    short* qk = (short*)out0;
#pragma unroll
    for (int mt = 0; mt < 4; ++mt) {
#pragma unroll
      for (int nt = 0; nt < 4; ++nt) {
        int col = col0 + wcol + nt * 16 + (lane & 15);
        float bv = bias[col];
        int rbase = row0 + wrow + mt * 16 + (lane >> 4) * 4;   // multiple of 4
        if (col < 4096) {
#pragma unroll
          for (int r = 0; r < 4; ++r)
            qk[(size_t)(rbase + r) * 4096 + col] = f2bf(acc[mt][nt][r] + bv);
        } else {
          // v third: pos = row & 1023 is 4 consecutive shorts, 8B-aligned -> 1 store
          int b = rbase >> 10, pos0 = rbase & 1023;
          int hd = col - 4096;
          short4 pk = make_short4(f2bf(acc[mt][nt][0] + bv), f2bf(acc[mt][nt][1] + bv),
                                  f2bf(acc[mt][nt][2] + bv), f2bf(acc[mt][nt][3] + bv));
          *(short4*)&vT[((size_t)b * 2048 + hd) * 1024 + pos0] = pk;
        }
      }
    }
  } else {
    float* out = (float*)out0;
#pragma unroll
    for (int mt = 0; mt < 4; ++mt) {
#pragma unroll
      for (int nt = 0; nt < 4; ++nt) {
        int col = col0 + wcol + nt * 16 + (lane & 15);
        float bv = bias[col];
#pragma unroll
        for (int r = 0; r < 4; ++r) {
          int row = row0 + wrow + mt * 16 + (lane >> 4) * 4 + r;
          out[(size_t)row * N + col] = acc[mt][nt][r] + bv;
        }
      }
    }
  }
}

// ---------------- flash attention v4: QBLK=128, 2 q-strips per wave (r20 best) ----
__global__ __launch_bounds__(256) void attn_kernel(const short* __restrict__ qk,
                                                   const short* __restrict__ vT,
                                                   short* __restrict__ att) {
  __shared__ __align__(16) short Ks[2][64][128];
  __shared__ __align__(16) short Vs[2][128][64];
  __shared__ __align__(16) short P[4][16][72];
  const int lane = threadIdx.x & 63;
  const int wid = threadIdx.x >> 6;
  const int bh = blockIdx.y;
  const int b = bh >> 4, h = bh & 15;
  const int q0 = blockIdx.x * 128 + wid * 16;

  const short* qbase = qk + (size_t)(b * 1024) * 4096 + h * 128;
  const short* kglob = qbase + 2048;
  const short* vglob = vT + (size_t)bh * 128 * 1024;

  bf16x8 qf[2][4];
#pragma unroll
  for (int s = 0; s < 2; ++s) {
    const int qrow = q0 + s * 64 + (lane & 15);
#pragma unroll
    for (int dc = 0; dc < 4; ++dc)
      qf[s][dc] = *(const bf16x8*)&qbase[(size_t)qrow * 4096 + dc * 32 + (lane >> 4) * 8];
  }

  const int krow_l = wid * 16 + (lane >> 4);
  const int kcol_l = (lane & 15) << 4;
  const int vrow_l = wid * 32 + (lane >> 3);
  const int vcol_l = (lane & 7) << 4;

#define STAGE_KV(buf, kv0)                                                              \
  {                                                                                     \
    _Pragma("unroll") for (int i = 0; i < 4; ++i) {                                     \
      int r = krow_l + i * 4;                                                           \
      const char* src = (const char*)(kglob + (size_t)((kv0) + r) * 4096) +             \
                        (kcol_l ^ ((r & 7) << 4));                                      \
      __builtin_amdgcn_global_load_lds(                                                 \
          (const __attribute__((address_space(1))) void*)src,                           \
          (__attribute__((address_space(3))) void*)&Ks[buf][wid * 16 + i * 4][0], 16,   \
          0, 0);                                                                        \
    }                                                                                   \
    _Pragma("unroll") for (int i = 0; i < 4; ++i) {                                     \
      int d = vrow_l + i * 8;                                                           \
      const char* src = (const char*)(vglob + (size_t)d * 1024 + (kv0)) +               \
                        (vcol_l ^ ((d & 7) << 4));                                      \
      __builtin_amdgcn_global_load_lds(                                                 \
          (const __attribute__((address_space(1))) void*)src,                           \
          (__attribute__((address_space(3))) void*)&Vs[buf][wid * 32 + i * 8][0], 16,   \
          0, 0);                                                                        \
    }                                                                                   \
  }

  float l_r[2][4] = {};
  f32x4 accO[2][8] = {};

  const float scale = 0.08838834764831845f;  // 1/sqrt(128)

  STAGE_KV(0, 0);
  asm volatile("s_waitcnt vmcnt(0)" ::: "memory");
  __builtin_amdgcn_s_barrier();
  __builtin_amdgcn_sched_barrier(0);

  int cur = 0;
  for (int t = 0; t < 16; ++t) {
    if (t < 15) STAGE_KV(cur ^ 1, (t + 1) * 64);

#pragma unroll
    for (int s = 0; s < 2; ++s) {
      f32x4 s4[4] = {};
#pragma unroll
      for (int kt = 0; kt < 4; ++kt) {
        const int row = kt * 16 + (lane & 15);
        const char* kr = (const char*)&Ks[cur][row][0];
        const int swz = (row & 7) << 4;
#pragma unroll
        for (int dc = 0; dc < 4; ++dc) {
          bf16x8 kf = *(const bf16x8*)(kr + ((dc * 64 + (lane >> 4) * 16) ^ swz));
          s4[kt] = __builtin_amdgcn_mfma_f32_16x16x32_bf16(qf[s][dc], kf, s4[kt], 0, 0, 0);
        }
      }

#pragma unroll
      for (int r = 0; r < 4; ++r) {
        float p0 = __expf(s4[0][r] * scale);
        float p1 = __expf(s4[1][r] * scale);
        float p2 = __expf(s4[2][r] * scale);
        float p3 = __expf(s4[3][r] * scale);
        l_r[s][r] += (p0 + p1) + (p2 + p3);
        int prow = (lane >> 4) * 4 + r;
        P[wid][prow][(lane & 15)] = f2bf(p0);
        P[wid][prow][16 + (lane & 15)] = f2bf(p1);
        P[wid][prow][32 + (lane & 15)] = f2bf(p2);
        P[wid][prow][48 + (lane & 15)] = f2bf(p3);
      }

      bf16x8 pf0 = *(const bf16x8*)&P[wid][lane & 15][(lane >> 4) * 8];
      bf16x8 pf1 = *(const bf16x8*)&P[wid][lane & 15][32 + (lane >> 4) * 8];

#pragma unroll
      for (int d0 = 0; d0 < 8; ++d0) {
        const int d = d0 * 16 + (lane & 15);
        const char* vr = (const char*)&Vs[cur][d][0];
        const int swz = (d & 7) << 4;
        bf16x8 vf0 = *(const bf16x8*)(vr + (((lane >> 4) * 16) ^ swz));
        bf16x8 vf1 = *(const bf16x8*)(vr + ((64 + (lane >> 4) * 16) ^ swz));
        accO[s][d0] = __builtin_amdgcn_mfma_f32_16x16x32_bf16(pf0, vf0, accO[s][d0], 0, 0, 0);
        accO[s][d0] = __builtin_amdgcn_mfma_f32_16x16x32_bf16(pf1, vf1, accO[s][d0], 0, 0, 0);
      }
    }

    asm volatile("s_waitcnt vmcnt(0)" ::: "memory");
    __builtin_amdgcn_s_barrier();
    __builtin_amdgcn_sched_barrier(0);
    cur ^= 1;
  }
#undef STAGE_KV

#pragma unroll
  for (int s = 0; s < 2; ++s) {
    float invl[4];
#pragma unroll
    for (int r = 0; r < 4; ++r) {
      float sum = l_r[s][r];
#pragma unroll
      for (int off = 1; off < 16; off <<= 1) sum += __shfl_xor(sum, off);
      invl[r] = 1.0f / sum;
    }
#pragma unroll
    for (int d0 = 0; d0 < 8; ++d0) {
#pragma unroll
      for (int r = 0; r < 4; ++r) {
        int arow = q0 + s * 64 + (lane >> 4) * 4 + r;
        att[(size_t)(b * 1024 + arow) * 2048 + h * 128 + d0 * 16 + (lane & 15)] =
            f2bf(accO[s][d0][r] * invl[r]);
      }
    }
  }
}

// ---------------- launch ----------------
extern "C" void kernel_launch(void* const* d_in, const int* in_sizes, int n_in,
                              void* d_out, int out_size, void* d_ws, size_t ws_size,
                              hipStream_t stream) {
  const float* x = (const float*)d_in[0];
  const float* Wqkv = (const float*)d_in[1];
  const float* bqkv = (const float*)d_in[2];
  const float* Wproj = (const float*)d_in[3];
  const float* bproj = (const float*)d_in[4];
  // d_in[5] = noise: provably unused (imag part never reaches the real output)
  float* out = (float*)d_out;

  char* ws = (char*)d_ws;
  short* xb = (short*)(ws + 0);
  short* Wqkvb = (short*)(ws + 16777216);
  short* Wprojb = (short*)(ws + 41943040);
  short* qkbuf = (short*)(ws + 50331648);
  short* vT = (short*)(ws + 83886080);
  short* attb = (short*)(ws + 100663296);

  hipLaunchKernelGGL(cast3_f32_bf16, dim3(3072), dim3(256), 0, stream,
                     x, xb, kM * kC / 4,
                     Wqkv, Wqkvb, k3C * kC / 4,
                     Wproj, Wprojb, kC * kC / 4);

  // QKV: BK=64 (r23 win) + packed vT stores (r25 win)
  hipLaunchKernelGGL((gemm_bt<0, 64>), dim3(kM / 128, k3C / 128), dim3(256), 0, stream,
                     xb, Wqkvb, bqkv, (void*)qkbuf, vT, kM, k3C, kC);

  hipLaunchKernelGGL(attn_kernel, dim3(kN / 128, kB * kH), dim3(256), 0, stream,
                     qkbuf, vT, attb);

  // proj: BK=64 (r24 win)
  hipLaunchKernelGGL((gemm_bt<1, 64>), dim3(kM / 128, kC / 128), dim3(256), 0, stream,
                     attb, Wprojb, bproj, (void*)out, (short*)nullptr, kM, kC, kC);
}